// Round 1
// baseline (1472.303 us; speedup 1.0000x reference)
//
#include <hip/hip_runtime.h>

// AdderNet-EDSR on MI355X. All adder layers are VALU-fp32 (no MFMA possible for L1-dist).
// Buffers in d_ws (floats): h, b0, b1, r (589824 each), ps (2359296). Total 18.87 MB.

enum { M_PLAIN = 0, M_RELU = 1, M_RES = 2, M_ADD = 3, M_PS = 4, M_HEAD = 5 };

__device__ __forceinline__ float mean_of(int c) {
    return c == 0 ? 0.4488f : (c == 1 ? 0.4371f : 0.404f);
}

// Block: 256 threads = 16 oc-groups (x4 oc) x 16 px-groups (x3 px).
// Tile: 64 oc x 48 px (one row, one batch). grid = (48 rows, 4 batch, COUT/64).
template <int CIN, int COUT, int MODE>
__global__ __launch_bounds__(256) void adder_kernel(const float* __restrict__ in,
                                                    const float* __restrict__ wgt,
                                                    const float* __restrict__ res,
                                                    float* __restrict__ out) {
    constexpr int ICC = (CIN < 16) ? CIN : 16;  // ic chunk
    constexpr int NCH = CIN / ICC;
    __shared__ __align__(16) float s_in[ICC][3][50];   // [ic][row y-1..y+1][padded col 0..49]
    __shared__ __align__(16) float s_w[ICC][9][64];    // [ic][k][oc]

    const int tid = threadIdx.x;
    const int y   = blockIdx.x;   // output row
    const int b   = blockIdx.y;   // batch
    const int ocb = blockIdx.z;   // 64-oc block

    const int ocg = tid & 15;     // 16 groups of 4 oc
    const int pxg = tid >> 4;     // 16 groups of 3 px
    const int x0  = pxg * 3;

    float acc[4][3];
#pragma unroll
    for (int o = 0; o < 4; ++o)
#pragma unroll
        for (int p = 0; p < 3; ++p) acc[o][p] = 0.f;

    for (int ch = 0; ch < NCH; ++ch) {
        const int ic0 = ch * ICC;
        // ---- stage input slab (zero-padded: pad contributes |0 - w| to the sum!) ----
        for (int i = tid; i < ICC * 150; i += 256) {
            const int c  = i % 50;
            const int rr = (i / 50) % 3;
            const int ic = i / 150;
            const int gy = y + rr - 1, gx = c - 1;
            float v = 0.f;
            if (gx >= 0 && gx < 48 && gy >= 0 && gy < 48) {
                v = in[((b * CIN + ic0 + ic) * 48 + gy) * 48 + gx];
                if (MODE == M_HEAD) v -= mean_of(ic0 + ic);
            }
            s_in[ic][rr][c] = v;
        }
        // ---- stage weights: s_w[ic][k][oc] ----
        for (int i = tid; i < ICC * 576; i += 256) {
            const int oc = i & 63;
            const int kk = (i >> 6) % 9;
            const int ic = i / 576;
            s_w[ic][kk][oc] = wgt[(ocb * 64 + oc) * (CIN * 9) + (ic0 + ic) * 9 + kk];
        }
        __syncthreads();

#pragma unroll 2
        for (int ic = 0; ic < ICC; ++ic) {
            float fin[3][5];
#pragma unroll
            for (int rr = 0; rr < 3; ++rr)
#pragma unroll
                for (int c = 0; c < 5; ++c) fin[rr][c] = s_in[ic][rr][x0 + c];
#pragma unroll
            for (int kk = 0; kk < 9; ++kk) {
                const float4 w4 = *(const float4*)&s_w[ic][kk][ocg * 4];
                const int dy = kk / 3, dx = kk % 3;
                const float wv[4] = {w4.x, w4.y, w4.z, w4.w};
#pragma unroll
                for (int o = 0; o < 4; ++o)
#pragma unroll
                    for (int p = 0; p < 3; ++p)
                        acc[o][p] -= fabsf(fin[dy][p + dx] - wv[o]);
            }
        }
        __syncthreads();
    }

    // ---- epilogue ----
#pragma unroll
    for (int o = 0; o < 4; ++o) {
        const int oc = ocb * 64 + ocg * 4 + o;
#pragma unroll
        for (int p = 0; p < 3; ++p) {
            const int x = x0 + p;
            float v = acc[o][p];
            if (MODE == M_RELU) v = fmaxf(v, 0.f);
            int oidx = ((b * COUT + oc) * 48 + y) * 48 + x;
            if (MODE == M_RES) v = res[oidx] + 0.1f * v;
            if (MODE == M_ADD) v = res[oidx] + v;
            if (MODE == M_PS) {
                // fused pixel-shuffle (r=2): ps[b][oc>>2][2y + ((oc>>1)&1)][2x + (oc&1)]
                oidx = ((b * 64 + (oc >> 2)) * 96 + (2 * y + ((oc >> 1) & 1))) * 96 +
                       (2 * x + (oc & 1));
            }
            out[oidx] = v;
        }
    }
}

// Tail: real conv 64->3 over the pixel-shuffled buffer ps[4][64][96][96], + bias + mean.
// Block 192 threads = 2 rows x 96 cols. grid = (48, 4).
__global__ __launch_bounds__(192) void tail_kernel(const float* __restrict__ ps,
                                                   const float* __restrict__ tw,
                                                   const float* __restrict__ tb,
                                                   float* __restrict__ out) {
    __shared__ float s_w[1728];  // [ic*9+k][oc]
    const int tid = threadIdx.x;
    for (int i = tid; i < 1728; i += 192) {
        const int oc  = i / 576;   // tw[oc][ic][ky][kx]
        const int rem = i % 576;   // ic*9+k
        s_w[rem * 3 + oc] = tw[oc * 576 + rem];
    }
    __syncthreads();

    const int b = blockIdx.y;
    const int Y = blockIdx.x * 2 + tid / 96;
    const int X = tid % 96;

    float acc[3] = {tb[0], tb[1], tb[2]};
    for (int ic = 0; ic < 64; ++ic) {
        float fin[3][3];
#pragma unroll
        for (int rr = 0; rr < 3; ++rr) {
            const int yy = Y + rr - 1;
#pragma unroll
            for (int c = 0; c < 3; ++c) {
                const int xx = X + c - 1;
                fin[rr][c] = (yy >= 0 && yy < 96 && xx >= 0 && xx < 96)
                                 ? ps[((b * 64 + ic) * 96 + yy) * 96 + xx]
                                 : 0.f;
            }
        }
#pragma unroll
        for (int kk = 0; kk < 9; ++kk) {
            const float* wr = &s_w[(ic * 9 + kk) * 3];
#pragma unroll
            for (int oc = 0; oc < 3; ++oc) acc[oc] += fin[kk / 3][kk % 3] * wr[oc];
        }
    }
#pragma unroll
    for (int oc = 0; oc < 3; ++oc)
        out[((b * 3 + oc) * 96 + Y) * 96 + X] = acc[oc] + mean_of(oc);
}

extern "C" void kernel_launch(void* const* d_in, const int* in_sizes, int n_in,
                              void* d_out, int out_size, void* d_ws, size_t ws_size,
                              hipStream_t stream) {
    const float* x      = (const float*)d_in[0];
    const float* head_w = (const float*)d_in[1];
    const float* rb_w1  = (const float*)d_in[2];
    const float* rb_w2  = (const float*)d_in[3];
    const float* body_w = (const float*)d_in[4];
    const float* up_w   = (const float*)d_in[5];
    const float* tail_w = (const float*)d_in[6];
    const float* tail_b = (const float*)d_in[7];
    float* out = (float*)d_out;

    float* ws = (float*)d_ws;
    float* h  = ws;
    float* b0 = ws + 589824;
    float* b1 = ws + 1179648;
    float* r  = ws + 1769472;
    float* ps = ws + 2359296;  // 2359296 floats

    const dim3 grid(48, 4, 1), blk(256);

    adder_kernel<3, 64, M_HEAD><<<grid, blk, 0, stream>>>(x, head_w, nullptr, h);

    const float* cur = h;
    float* nxt = b0;
    for (int k = 0; k < 8; ++k) {
        adder_kernel<64, 64, M_RELU><<<grid, blk, 0, stream>>>(cur, rb_w1 + k * 36864,
                                                               nullptr, r);
        adder_kernel<64, 64, M_RES><<<grid, blk, 0, stream>>>(r, rb_w2 + k * 36864, cur,
                                                              nxt);
        cur = nxt;
        nxt = (nxt == b0) ? b1 : b0;
    }
    // body + skip (res = h + body(b))
    adder_kernel<64, 64, M_ADD><<<grid, blk, 0, stream>>>(cur, body_w, h, nxt);
    // up (Cout=256) with fused pixel-shuffle store
    adder_kernel<64, 256, M_PS><<<dim3(48, 4, 4), blk, 0, stream>>>(nxt, up_w, nullptr, ps);
    // tail conv + bias + mean
    tail_kernel<<<dim3(48, 4), dim3(192), 0, stream>>>(ps, tail_w, tail_b, out);
}

// Round 2
// 1047.189 us; speedup vs baseline: 1.4060x; 1.4060x over previous
//
#include <hip/hip_runtime.h>

// AdderNet-EDSR on MI355X. Pure VALU-fp32 workload (L1-dist has no matmul form).
// Round 2: occupancy restructure. 128-thread blocks (2 waves x 4 oc each, shared
// 4x16 px tile), 4 accs/thread -> 2304 waves/layer (2.25/SIMD). Weights
// pre-transposed to [ic][k][oc] so block staging is coalesced float4 and the
// inner-loop weight read is a wave-uniform broadcast ds_read_b128.

enum { M_PLAIN = 0, M_RELU = 1, M_RES = 2, M_ADD = 3, M_PS = 4, M_HEAD = 5 };

__device__ __forceinline__ float mean_of(int c) {
    return c == 0 ? 0.4488f : (c == 1 ? 0.4371f : 0.404f);
}

// ---- weight transpose: w[oc][ic][k] -> wt[ic][k][oc], per layer (blockIdx.y) ----
template <int CIN, int COUT>
__global__ __launch_bounds__(256) void wtr_kernel(const float* __restrict__ w,
                                                  float* __restrict__ wt) {
    const int L = CIN * COUT * 9;
    const int id = blockIdx.x * 256 + threadIdx.x;
    const float* src = w + blockIdx.y * L;
    float* dst = wt + blockIdx.y * L;
    if (id < L) {
        const int oc = id / (CIN * 9);
        const int r  = id % (CIN * 9);
        const int ic = r / 9, kk = r % 9;
        dst[(ic * 9 + kk) * COUT + oc] = src[id];
    }
}

// ---- adder layer ----
// block = 128 threads = 2 waves; wave w handles oc_base = blockIdx.y*8 + w*4 (4 oc),
// lane = px in a 4x16 tile. grid = (36 px-tiles, COUT/8, 4 batch).
template <int CIN, int COUT, int MODE>
__global__ __launch_bounds__(128) void adder_kernel(const float* __restrict__ in,
                                                    const float* __restrict__ wt,
                                                    const float* __restrict__ res,
                                                    float* __restrict__ out) {
    constexpr int ICC = (CIN < 16) ? CIN : 16;
    constexpr int NCH = CIN / ICC;
    __shared__ __align__(16) float s_in[ICC][6][20];  // rows y0-1..y0+4, cols x0-1..x0+16
    __shared__ __align__(16) float s_w[ICC][9][8];    // [ic][k][oc within block]

    const int tid  = threadIdx.x;
    const int wave = tid >> 6;
    const int lane = tid & 63;
    const int ly = lane >> 4, lx = lane & 15;

    const int t   = blockIdx.x;  // 36 px tiles (12 y-tiles x 3 x-tiles)
    const int y0  = (t / 3) * 4, x0 = (t % 3) * 16;
    const int ocb = blockIdx.y;
    const int b   = blockIdx.z;

    const int y = y0 + ly, x = x0 + lx;
    const int oc_base = ocb * 8 + wave * 4;

    float acc0 = 0.f, acc1 = 0.f, acc2 = 0.f, acc3 = 0.f;

    for (int ch = 0; ch < NCH; ++ch) {
        const int ic0 = ch * ICC;
        // stage input slab (zero-padded: pad still contributes -|w| downstream)
        for (int i = tid; i < ICC * 108; i += 128) {
            const int ic = i / 108, rem = i % 108, rr = rem / 18, cc = rem % 18;
            const int gy = y0 + rr - 1, gx = x0 + cc - 1;
            float v = 0.f;
            if ((unsigned)gy < 48u && (unsigned)gx < 48u) {
                v = in[((b * CIN + ic0 + ic) * 48 + gy) * 48 + gx];
                if (MODE == M_HEAD) v -= mean_of(ic0 + ic);
            }
            s_in[ic][rr][cc] = v;
        }
        // stage weights (coalesced float4 from transposed layout)
        for (int i = tid; i < ICC * 18; i += 128) {
            const int ic = i / 18, rem = i % 18, kk = rem >> 1, j = rem & 1;
            const float4 wv =
                *(const float4*)&wt[((ic0 + ic) * 9 + kk) * COUT + ocb * 8 + j * 4];
            *(float4*)&s_w[ic][kk][j * 4] = wv;
        }
        __syncthreads();

#pragma unroll 4
        for (int ic = 0; ic < ICC; ++ic) {
            float f[3][3];
#pragma unroll
            for (int dy = 0; dy < 3; ++dy)
#pragma unroll
                for (int dx = 0; dx < 3; ++dx) f[dy][dx] = s_in[ic][ly + dy][lx + dx];
#pragma unroll
            for (int kk = 0; kk < 9; ++kk) {
                const float4 w4 = *(const float4*)&s_w[ic][kk][wave * 4];  // broadcast
                const float fv = f[kk / 3][kk % 3];
                acc0 -= fabsf(fv - w4.x);
                acc1 -= fabsf(fv - w4.y);
                acc2 -= fabsf(fv - w4.z);
                acc3 -= fabsf(fv - w4.w);
            }
        }
        __syncthreads();
    }

    const float accs[4] = {acc0, acc1, acc2, acc3};
#pragma unroll
    for (int o = 0; o < 4; ++o) {
        const int oc = oc_base + o;
        float v = accs[o];
        int idx = ((b * COUT + oc) * 48 + y) * 48 + x;
        if (MODE == M_RELU) v = fmaxf(v, 0.f);
        if (MODE == M_RES) v = res[idx] + 0.1f * v;
        if (MODE == M_ADD) v = res[idx] + v;
        if (MODE == M_PS)
            idx = ((b * 64 + (oc >> 2)) * 96 + (2 * y + ((oc >> 1) & 1))) * 96 +
                  (2 * x + (oc & 1));
        out[idx] = v;
    }
}

// ---- tail: real conv 64->3 over ps[4][64][96][96], + bias + mean ----
__global__ __launch_bounds__(256) void tail_kernel(const float* __restrict__ ps,
                                                   const float* __restrict__ tw,
                                                   const float* __restrict__ tb,
                                                   float* __restrict__ out) {
    __shared__ float s_w[1728];  // [ic*9+k][oc]
    const int tid = threadIdx.x;
    for (int i = tid; i < 1728; i += 256) {
        const int oc = i / 576, rem = i % 576;
        s_w[rem * 3 + oc] = tw[i];
    }
    __syncthreads();

    const int gid = blockIdx.x * 256 + tid;  // 36864 px total
    const int b = gid / 9216;
    const int p = gid % 9216;
    const int Y = p / 96, X = p % 96;

    float a0 = tb[0], a1 = tb[1], a2 = tb[2];
    for (int ic = 0; ic < 64; ++ic) {
        const float* base = ps + (b * 64 + ic) * 9216;
#pragma unroll
        for (int kk = 0; kk < 9; ++kk) {
            const int yy = Y + kk / 3 - 1, xx = X + kk % 3 - 1;
            float fv = 0.f;
            if ((unsigned)yy < 96u && (unsigned)xx < 96u) fv = base[yy * 96 + xx];
            const float* wr = &s_w[(ic * 9 + kk) * 3];
            a0 += fv * wr[0];
            a1 += fv * wr[1];
            a2 += fv * wr[2];
        }
    }
    out[((b * 3 + 0) * 96 + Y) * 96 + X] = a0 + mean_of(0);
    out[((b * 3 + 1) * 96 + Y) * 96 + X] = a1 + mean_of(1);
    out[((b * 3 + 2) * 96 + Y) * 96 + X] = a2 + mean_of(2);
}

extern "C" void kernel_launch(void* const* d_in, const int* in_sizes, int n_in,
                              void* d_out, int out_size, void* d_ws, size_t ws_size,
                              hipStream_t stream) {
    const float* x      = (const float*)d_in[0];
    const float* head_w = (const float*)d_in[1];
    const float* rb_w1  = (const float*)d_in[2];
    const float* rb_w2  = (const float*)d_in[3];
    const float* body_w = (const float*)d_in[4];
    const float* up_w   = (const float*)d_in[5];
    const float* tail_w = (const float*)d_in[6];
    const float* tail_b = (const float*)d_in[7];
    float* out = (float*)d_out;

    // ws layout (floats). S = one activation plane (4*64*48*48).
    // ps (4*64*96*96 = 4S) aliases s0..s3, which are all dead by the time `up` runs.
    constexpr int S = 589824;
    float* ws = (float*)d_ws;
    float* s0 = ws;           // h
    float* s1 = ws + 1 * S;   // b-chain
    float* s2 = ws + 2 * S;   // b-chain
    float* s3 = ws + 3 * S;   // r
    float* s4 = ws + 4 * S;   // body output (up input)
    float* ps = ws;           // spans s0..s3
    float* wtH = ws + 5 * S;                  // 1728
    float* wt1 = wtH + 1728;                  // 8 x 36864
    float* wt2 = wt1 + 8 * 36864;             // 8 x 36864
    float* wtB = wt2 + 8 * 36864;             // 36864
    float* wtU = wtB + 36864;                 // 147456

    // ---- weight transposes ----
    wtr_kernel<3, 64><<<dim3(7, 1), 256, 0, stream>>>(head_w, wtH);
    wtr_kernel<64, 64><<<dim3(144, 8), 256, 0, stream>>>(rb_w1, wt1);
    wtr_kernel<64, 64><<<dim3(144, 8), 256, 0, stream>>>(rb_w2, wt2);
    wtr_kernel<64, 64><<<dim3(144, 1), 256, 0, stream>>>(body_w, wtB);
    wtr_kernel<64, 256><<<dim3(576, 1), 256, 0, stream>>>(up_w, wtU);

    const dim3 blk(128);
    const dim3 gmid(36, 8, 4);   // 1152 blocks

    adder_kernel<3, 64, M_HEAD><<<gmid, blk, 0, stream>>>(x, wtH, nullptr, s0);

    const float* cur = s0;
    float* bufs[2] = {s1, s2};
    for (int k = 0; k < 8; ++k) {
        adder_kernel<64, 64, M_RELU><<<gmid, blk, 0, stream>>>(cur, wt1 + k * 36864,
                                                               nullptr, s3);
        adder_kernel<64, 64, M_RES><<<gmid, blk, 0, stream>>>(s3, wt2 + k * 36864, cur,
                                                              bufs[k & 1]);
        cur = bufs[k & 1];
    }
    // body + global skip: s4 = h + body(cur)
    adder_kernel<64, 64, M_ADD><<<gmid, blk, 0, stream>>>(cur, wtB, s0, s4);
    // up (Cout=256) with fused pixel-shuffle into ps (aliases s0..s3; s4 is safe)
    adder_kernel<64, 256, M_PS><<<dim3(36, 32, 4), blk, 0, stream>>>(s4, wtU, nullptr, ps);
    // tail conv + bias + mean
    tail_kernel<<<dim3(144), dim3(256), 0, stream>>>(ps, tail_w, tail_b, out);
}